// Round 3
// baseline (302.564 us; speedup 1.0000x reference)
//
#include <hip/hip_runtime.h>
#include <cstdint>

// B=4, L=2048, H=512, HEADS=8, D=64.
// Only the DIAGONAL of softmax(scores) is consumed:
//   diag_i = exp(s_ii) / sum_j exp(s_ij),
//   s_ij = q_i.k_j + q_i.Wp[2047+j-i (padded)] + Wp_b[2047+j-i]
// Logits in log2 units (q pre-scaled by log2e/8 via prep-scaled Wq, bias by log2e).

typedef unsigned short u16;
typedef __bf16 bf16x8 __attribute__((ext_vector_type(8)));
typedef __bf16 bf16x2 __attribute__((ext_vector_type(2)));
typedef float  f32x16 __attribute__((ext_vector_type(16)));
typedef uint32_t __attribute__((address_space(1))) as1_u32;
typedef uint32_t __attribute__((address_space(3))) as3_u32;

__device__ __forceinline__ u16 f2bf(float f) {
  __bf16 h = (__bf16)f;
  return __builtin_bit_cast(u16, h);
}
__device__ __forceinline__ uint32_t pkbf(float a, float b) {
  bf16x2 v; v[0] = (__bf16)a; v[1] = (__bf16)b;
  return __builtin_bit_cast(uint32_t, v);
}
__device__ __forceinline__ float bf2f(u16 u) {
  return __uint_as_float(((uint32_t)u) << 16);
}
__device__ __forceinline__ float exp2v(float x) {
  float r;
  asm("v_exp_f32 %0, %1" : "=v"(r) : "v"(x));
  return r;
}
__device__ __forceinline__ void gl_lds16(const void* g, void* l) {
  __builtin_amdgcn_global_load_lds((const as1_u32*)g, (as3_u32*)l, 16, 0, 0);
}

// ---------------------------------------------------------------------------
// Prep: fp32 -> bf16 for q_in/k_in/v_in, Wq/Wk/Wv/Wo, Wp (padded to 4096 rows)
// Wq is pre-scaled by log2e/8 so the QKV epilogue needs no multiply.
// ---------------------------------------------------------------------------
__global__ __launch_bounds__(256) void prep_kernel(
    const float* __restrict__ qin, const float* __restrict__ kin, const float* __restrict__ vin,
    const float* __restrict__ wq,  const float* __restrict__ wk,  const float* __restrict__ wv,
    const float* __restrict__ wo,  const float* __restrict__ wp,
    u16* __restrict__ xq, u16* __restrict__ xk, u16* __restrict__ xv,
    u16* __restrict__ bwq, u16* __restrict__ bwk, u16* __restrict__ bwv,
    u16* __restrict__ bwo, u16* __restrict__ bwp) {
  long u = (long)blockIdx.x * 256 + threadIdx.x;
  const float* src; u16* dst; long off; float qs = 1.0f;
  if      (u < 524288L)  { src = qin; dst = xq;  off = u; }
  else if (u < 1048576L) { src = kin; dst = xk;  off = u - 524288L; }
  else if (u < 1572864L) { src = vin; dst = xv;  off = u - 1048576L; }
  else if (u < 1605632L) { src = wq;  dst = bwq; off = u - 1572864L; qs = 0.18033688f; }
  else if (u < 1638400L) { src = wk;  dst = bwk; off = u - 1605632L; }
  else if (u < 1671168L) { src = wv;  dst = bwv; off = u - 1638400L; }
  else if (u < 1703936L) { src = wo;  dst = bwo; off = u - 1671168L; }
  else if (u < 1736696L) { src = wp;  dst = bwp; off = u - 1703936L; }
  else {  // zero-fill Wp pad row 4095
    long o = (u - 1736696L) * 8 + 262080L;
    uint4 z = {0u, 0u, 0u, 0u};
    *(uint4*)(bwp + o) = z;
    return;
  }
  const float4* s4 = (const float4*)(src + off * 8);
  float4 a = s4[0], b = s4[1];
  uint32_t p0 = pkbf(a.x * qs, a.y * qs);
  uint32_t p1 = pkbf(a.z * qs, a.w * qs);
  uint32_t p2 = pkbf(b.x * qs, b.y * qs);
  uint32_t p3 = pkbf(b.z * qs, b.w * qs);
  uint4 o = {p0, p1, p2, p3};
  *(uint4*)(dst + off * 8) = o;
}

// ---------------------------------------------------------------------------
// 64x64-tile GEMM core (C = A @ W^T), 4 waves, each wave one 32x32 quadrant.
// ---------------------------------------------------------------------------
__device__ __forceinline__ void gemm64_core(
    const u16* __restrict__ A, const u16* __restrict__ W, int m0, int n0,
    u16* Al, u16* Bl, int tid, f32x16& acc) {
  const int lane = tid & 63, w = tid >> 6;
  const int wi = w >> 1, wj = w & 1;
  const int l31 = lane & 31, lh = lane >> 5;
  const int r = tid >> 2, ch = tid & 3;
  const int gch = ch ^ ((r >> 1) & 3);
  for (int kb = 0; kb < 16; ++kb) {
    gl_lds16(A + (long)(m0 + r) * 512 + kb * 32 + gch * 8, (char*)Al + w * 64 * 16);
    gl_lds16(W + (long)(n0 + r) * 512 + kb * 32 + gch * 8, (char*)Bl + w * 64 * 16);
    __syncthreads();
    bf16x8 af[2], bfr[2];
#pragma unroll
    for (int ks = 0; ks < 2; ++ks) {
      int c2 = 2 * ks + lh;
      int rA = 32 * wi + l31;
      int rB = 32 * wj + l31;
      af[ks]  = *(const bf16x8*)((char*)Al + (rA * 4 + (c2 ^ ((rA >> 1) & 3))) * 16);
      bfr[ks] = *(const bf16x8*)((char*)Bl + (rB * 4 + (c2 ^ ((rB >> 1) & 3))) * 16);
    }
#pragma unroll
    for (int ks = 0; ks < 2; ++ks)
      acc = __builtin_amdgcn_mfma_f32_32x32x16_bf16(af[ks], bfr[ks], acc, 0, 0, 0);
    __syncthreads();
  }
}

// gemm_bt: final projection, fp32 out row-major. 1024 blocks.
__global__ __launch_bounds__(256, 4) void gemm_bt(
    const u16* __restrict__ A, const u16* __restrict__ W, const float* __restrict__ bias,
    float* __restrict__ ofp) {
  __shared__ u16 Al[64 * 32];
  __shared__ u16 Bl[64 * 32];
  const int tid = threadIdx.x;
  const int lane = tid & 63, w = tid >> 6;
  const int wi = w >> 1, wj = w & 1;
  const int l31 = lane & 31, lh = lane >> 5;
  const int u = (blockIdx.x & 7) * 128 + (blockIdx.x >> 3);
  const int m0 = (u >> 3) * 64, n0 = (u & 7) * 64;

  float bv = bias[n0 + 32 * wj + l31];
  f32x16 acc;
#pragma unroll
  for (int rr = 0; rr < 16; ++rr) acc[rr] = bv;

  gemm64_core(A, W, m0, n0, Al, Bl, tid, acc);

  int n = n0 + 32 * wj + l31;
#pragma unroll
  for (int rr = 0; rr < 16; ++rr) {
    int row = m0 + 32 * wi + (rr & 3) + 8 * (rr >> 2) + 4 * lh;
    ofp[(long)row * 512 + n] = acc[rr];
  }
}

// qkv_gemm: 3072 blocks (3 mats x 1024), bf16 out in (b,h,l,d).
__global__ __launch_bounds__(256, 4) void qkv_gemm(
    const u16* __restrict__ xq, const u16* __restrict__ xk, const u16* __restrict__ xv,
    const u16* __restrict__ wqp, const u16* __restrict__ wkp, const u16* __restrict__ wvp,
    const float* __restrict__ bq, const float* __restrict__ bk, const float* __restrict__ bv,
    u16* __restrict__ oq, u16* __restrict__ ok, u16* __restrict__ ov) {
  __shared__ u16 Al[64 * 32];
  __shared__ u16 Bl[64 * 32];
  const int mat = blockIdx.x >> 10;
  const int t = blockIdx.x & 1023;
  const u16* A = (mat == 0) ? xq : (mat == 1) ? xk : xv;
  const u16* W = (mat == 0) ? wqp : (mat == 1) ? wkp : wvp;
  const float* bias = (mat == 0) ? bq : (mat == 1) ? bk : bv;
  u16* obf = (mat == 0) ? oq : (mat == 1) ? ok : ov;
  const float bsc = (mat == 0) ? 0.18033688f : 1.0f;

  const int tid = threadIdx.x;
  const int lane = tid & 63, w = tid >> 6;
  const int wi = w >> 1, wj = w & 1;
  const int l31 = lane & 31, lh = lane >> 5;
  const int u = (t & 7) * 128 + (t >> 3);
  const int m0 = (u >> 3) * 64, n0 = (u & 7) * 64;

  float bvv = bias[n0 + 32 * wj + l31] * bsc;
  f32x16 acc;
#pragma unroll
  for (int rr = 0; rr < 16; ++rr) acc[rr] = bvv;

  gemm64_core(A, W, m0, n0, Al, Bl, tid, acc);

  int n = n0 + 32 * wj + l31;
  int h = n >> 6, d = n & 63;
#pragma unroll
  for (int rr = 0; rr < 16; ++rr) {
    int row = m0 + 32 * wi + (rr & 3) + 8 * (rr >> 2) + 4 * lh;
    int b = row >> 11, l = row & 2047;
    obf[(((long)(b * 8 + h)) * 2048 + l) * 64 + d] = f2bf(acc[rr]);
  }
}

// ---------------------------------------------------------------------------
// Attention v3: BARRIER-FREE main loop. One block per (b,h, 64-row i-tile);
// 4 fully independent waves. Wave (wi,wj): rows [r0,r0+32), cols
// [1024wj + 32t), t=0..31. Per iter the wave computes its own 32x32 score
// tile AND its own P tile (rolling 64-row Wp window, tile B_t = A_{t+1}),
// so the skew gather is WAVE-LOCAL: for reg r, the needed window element
// sits at lane (l31 + 31-lrr-4lh)&31 of P-tile A or B — one cndmask (A/B by
// source lane: t' >= 31-lrr) + one ds_bpermute per reg. P stays f32.
// 3-buffer rotation: B_{t+1} is computed one iter AHEAD, so the gather never
// waits on the current MFMA chain. Total MFMA/block unchanged (1024).
// Window math: W(j,r) = 2047+j-r; wbase_t = 2016+c0-r0+32t; idx = W-wbase =
// 31 + l31 - lrr - 4lh in [0,62]. Max Wp row touched = 4095 (zero pad row).
// ---------------------------------------------------------------------------
__global__ __launch_bounds__(256, 3) void attn_kernel(
    const u16* __restrict__ qw, const u16* __restrict__ kw, const u16* __restrict__ vw,
    const u16* __restrict__ wpw, const float* __restrict__ wpb, u16* __restrict__ outp) {
  __shared__ float sdiag[64];
  __shared__ float rssum[128];
  __shared__ float attw[64];

  const int tid = threadIdx.x, lane = tid & 63, w = tid >> 6;
  const int wi = w >> 1, wj = w & 1;
  const int sbi = blockIdx.x;
  const int kk_ = sbi >> 3;
  const int bh = (sbi & 7) + 8 * (kk_ >> 5);   // XCD swizzle: 32 i-tiles/bh per XCD
  const int it = kk_ & 31;
  const int i0 = it * 64;
  const u16* qb = qw + (long)bh * 2048 * 64;
  const u16* kb = kw + (long)bh * 2048 * 64;
  const u16* vb = vw + (long)bh * 2048 * 64;

  const int l31 = lane & 31, lh = lane >> 5;
  const int r0 = i0 + 32 * wi;
  const int c0b = 1024 * wj;
  const int wb = 2016 + c0b - r0;              // window base at t=0
  const int tsel = l31 + 4 * lh;               // source-lane A/B select key
  const int lbb = l31 + 31 - 4 * lh;           // bpermute index base
  const int hb = 128 * lh;                     // byte base of this 32-half

  // A-fragments: Q rows r0 + l31, full K=64 (log2e/8 pre-scaled)
  bf16x8 aq[4];
  {
    const u16* p = qb + (long)(r0 + l31) * 64 + lh * 8;
#pragma unroll
    for (int kk = 0; kk < 4; ++kk) aq[kk] = *(const bf16x8*)(p + kk * 16);
  }

  float rsum[16];
#pragma unroll
  for (int r = 0; r < 16; ++r) rsum[r] = 0.f;

  int td = -1;  // iteration holding this wave's diagonal (if any)
  {
    int tdn = r0 - c0b;
    if (tdn >= 0 && tdn < 1024) td = tdn >> 5;
  }

  // compute P tile: P[row][widx + (lane&31)] over 32 window rows, bias C-init
  auto ptile = [&](int widx, f32x16& P) {
    int wr = widx + l31;
    const u16* bp = wpw + (long)wr * 64 + lh * 8;
    bf16x8 bw[4];
#pragma unroll
    for (int kk = 0; kk < 4; ++kk) bw[kk] = *(const bf16x8*)(bp + kk * 16);
    float bv = wpb[wr > 4094 ? 4094 : wr] * 1.44269504f;
#pragma unroll
    for (int r = 0; r < 16; ++r) P[r] = bv;
#pragma unroll
    for (int kk = 0; kk < 4; ++kk)
      P = __builtin_amdgcn_mfma_f32_32x32x16_bf16(aq[kk], bw[kk], P, 0, 0, 0);
  };

  f32x16 P0, P1, P2;
  ptile(wb, P0);        // A_0
  ptile(wb + 32, P1);   // B_0

  auto step = [&](int t, f32x16& PA, f32x16& PB, f32x16& PN, bool last) {
    // K fragments for this 32-col chunk: global -> VGPR
    int c0 = c0b + 32 * t;
    const u16* kp = kb + (long)(c0 + l31) * 64 + lh * 8;
    bf16x8 kf[4];
#pragma unroll
    for (int kk = 0; kk < 4; ++kk) kf[kk] = *(const bf16x8*)(kp + kk * 16);

    // skew gather from the two ready P tiles -> score C-init (f32, in-wave)
    f32x16 accS;
#pragma unroll
    for (int r = 0; r < 16; ++r) {
      const int lrr = (r & 3) + 8 * (r >> 2);
      float M = (tsel >= 31 - lrr) ? PA[r] : PB[r];
      int gi = __builtin_amdgcn_ds_bpermute((((lbb - lrr) & 31) << 2) + hb,
                                            __float_as_int(M));
      accS[r] = __int_as_float(gi);
    }

    // next window tile (B_{t+1}) — one iteration ahead of its gather
    if (!last) ptile(wb + 32 * (t + 2), PN);

    // score chain on top of gathered P
#pragma unroll
    for (int kk = 0; kk < 4; ++kk)
      accS = __builtin_amdgcn_mfma_f32_32x32x16_bf16(aq[kk], kf[kk], accS, 0, 0, 0);

#pragma unroll
    for (int r = 0; r < 16; ++r) rsum[r] += exp2v(accS[r]);

    if (t == td) {  // wave-uniform: this chunk holds the diagonal
#pragma unroll
      for (int r = 0; r < 16; ++r) {
        const int lrr = (r & 3) + 8 * (r >> 2);
        if (l31 == lrr + 4 * lh) sdiag[32 * wi + l31] = accS[r];
      }
    }
  };

  for (int tt = 0; tt < 30; tt += 3) {
    step(tt,     P0, P1, P2, false);
    step(tt + 1, P1, P2, P0, false);
    step(tt + 2, P2, P0, P1, false);
  }
  step(30, P0, P1, P2, false);
  step(31, P1, P2, P0, true);

  // reduce row partials across the 32 lanes sharing each row
#pragma unroll
  for (int r = 0; r < 16; ++r) {
    float v = rsum[r];
    v += __shfl_xor(v, 1);
    v += __shfl_xor(v, 2);
    v += __shfl_xor(v, 4);
    v += __shfl_xor(v, 8);
    v += __shfl_xor(v, 16);
    rsum[r] = v;
  }
  if (l31 == 0) {
#pragma unroll
    for (int r = 0; r < 16; ++r) {
      int lr = (r & 3) + 8 * (r >> 2) + 4 * lh;
      rssum[(32 * wi + lr) * 2 + wj] = rsum[r];
    }
  }
  __syncthreads();
  if (tid < 64) {
    float S = rssum[2 * tid] + rssum[2 * tid + 1];
    attw[tid] = exp2v(sdiag[tid]) / S;
  }
  __syncthreads();
  // out_pre[b*2048 + i][h*64 + d] = diag * v   (bf16)
  {
    int r = tid >> 2, dd = (tid & 3) * 16;
    float a = attw[r];
    int b = bh >> 3, h = bh & 7;
    const u16* vp = vb + (long)(i0 + r) * 64 + dd;
    u16* op = outp + ((long)(b * 2048 + i0 + r)) * 512 + h * 64 + dd;
    uint4 v0 = *(const uint4*)vp;
    uint4 v1 = *(const uint4*)(vp + 8);
    uint32_t vin[8] = {v0.x, v0.y, v0.z, v0.w, v1.x, v1.y, v1.z, v1.w};
    uint32_t vout[8];
#pragma unroll
    for (int e = 0; e < 8; ++e) {
      float lo = bf2f((u16)(vin[e] & 0xffffu)) * a;
      float hi = bf2f((u16)(vin[e] >> 16)) * a;
      vout[e] = pkbf(lo, hi);
    }
    uint4 o0 = {vout[0], vout[1], vout[2], vout[3]};
    uint4 o1 = {vout[4], vout[5], vout[6], vout[7]};
    *(uint4*)op = o0;
    *(uint4*)(op + 8) = o1;
  }
}

// ---------------------------------------------------------------------------
extern "C" void kernel_launch(void* const* d_in, const int* in_sizes, int n_in,
                              void* d_out, int out_size, void* d_ws, size_t ws_size,
                              hipStream_t stream) {
  (void)in_sizes; (void)n_in; (void)out_size; (void)ws_size;
  const float* q_in = (const float*)d_in[0];
  const float* k_in = (const float*)d_in[1];
  const float* v_in = (const float*)d_in[2];
  const float* Wq_w = (const float*)d_in[3];
  const float* Wq_b = (const float*)d_in[4];
  const float* Wk_w = (const float*)d_in[5];
  const float* Wk_b = (const float*)d_in[6];
  const float* Wv_w = (const float*)d_in[7];
  const float* Wv_b = (const float*)d_in[8];
  const float* Wo_w = (const float*)d_in[9];
  const float* Wo_b = (const float*)d_in[10];
  const float* Wp_w = (const float*)d_in[11];
  const float* Wp_b = (const float*)d_in[12];

  char* ws = (char*)d_ws;
  u16* xq   = (u16*)(ws + 0);         // 8 MB  bf16 q_in
  u16* xk   = (u16*)(ws + 8388608);   // 8 MB
  u16* xv   = (u16*)(ws + 16777216);  // 8 MB
  u16* wq   = (u16*)(ws + 25165824);  // 512 KB each
  u16* wk   = (u16*)(ws + 25690112);
  u16* wv   = (u16*)(ws + 26214400);
  u16* wo   = (u16*)(ws + 26738688);
  u16* wp   = (u16*)(ws + 27262976);  // 4096x64 bf16 (row 4095 zero)
  u16* q_ws = (u16*)(ws + 27787264);  // (b,h,l,d) bf16, pre-scaled log2e/8
  u16* k_ws = (u16*)(ws + 36175872);
  u16* v_ws = (u16*)(ws + 44564480);
  u16* opre = (u16*)(ws + 52953088);  // (b*l, h*d) bf16 diag-scaled v

  prep_kernel<<<6784, 256, 0, stream>>>(q_in, k_in, v_in, Wq_w, Wk_w, Wv_w, Wo_w, Wp_w,
                                        xq, xk, xv, wq, wk, wv, wo, wp);
  qkv_gemm<<<3072, 256, 0, stream>>>(xq, xk, xv, wq, wk, wv, Wq_b, Wk_b, Wv_b,
                                     q_ws, k_ws, v_ws);
  attn_kernel<<<1024, 256, 0, stream>>>(q_ws, k_ws, v_ws, wp, Wp_b, opre);
  gemm_bt<<<1024, 256, 0, stream>>>(opre, wo, Wo_b, (float*)d_out);
}

// Round 4
// 284.297 us; speedup vs baseline: 1.0643x; 1.0643x over previous
//
#include <hip/hip_runtime.h>
#include <cstdint>

// B=4, L=2048, H=512, HEADS=8, D=64.
// Only the DIAGONAL of softmax(scores) is consumed:
//   diag_i = exp(s_ii) / sum_j exp(s_ij),
//   s_ij = q_i.k_j + q_i.Wp[2047+j-i (padded)] + Wp_b[2047+j-i]
// Logits in log2 units (q pre-scaled by log2e/8 via prep-scaled Wq, bias by log2e).

typedef unsigned short u16;
typedef __bf16 bf16x8 __attribute__((ext_vector_type(8)));
typedef __bf16 bf16x2 __attribute__((ext_vector_type(2)));
typedef float  f32x16 __attribute__((ext_vector_type(16)));
typedef uint32_t __attribute__((address_space(1))) as1_u32;
typedef uint32_t __attribute__((address_space(3))) as3_u32;

__device__ __forceinline__ u16 f2bf(float f) {
  __bf16 h = (__bf16)f;
  return __builtin_bit_cast(u16, h);
}
__device__ __forceinline__ uint32_t pkbf(float a, float b) {
  bf16x2 v; v[0] = (__bf16)a; v[1] = (__bf16)b;
  return __builtin_bit_cast(uint32_t, v);
}
__device__ __forceinline__ float bf2f(u16 u) {
  return __uint_as_float(((uint32_t)u) << 16);
}
__device__ __forceinline__ float exp2v(float x) {
  float r;
  asm("v_exp_f32 %0, %1" : "=v"(r) : "v"(x));
  return r;
}
__device__ __forceinline__ void gl_lds16(const void* g, void* l) {
  __builtin_amdgcn_global_load_lds((const as1_u32*)g, (as3_u32*)l, 16, 0, 0);
}

// ---------------------------------------------------------------------------
// Prep: fp32 -> bf16 for q_in/k_in/v_in, Wq/Wk/Wv/Wo, Wp (padded to 4096 rows)
// Wq is pre-scaled by log2e/8 so the QKV epilogue needs no multiply.
// ---------------------------------------------------------------------------
__global__ __launch_bounds__(256) void prep_kernel(
    const float* __restrict__ qin, const float* __restrict__ kin, const float* __restrict__ vin,
    const float* __restrict__ wq,  const float* __restrict__ wk,  const float* __restrict__ wv,
    const float* __restrict__ wo,  const float* __restrict__ wp,
    u16* __restrict__ xq, u16* __restrict__ xk, u16* __restrict__ xv,
    u16* __restrict__ bwq, u16* __restrict__ bwk, u16* __restrict__ bwv,
    u16* __restrict__ bwo, u16* __restrict__ bwp) {
  long u = (long)blockIdx.x * 256 + threadIdx.x;
  const float* src; u16* dst; long off; float qs = 1.0f;
  if      (u < 524288L)  { src = qin; dst = xq;  off = u; }
  else if (u < 1048576L) { src = kin; dst = xk;  off = u - 524288L; }
  else if (u < 1572864L) { src = vin; dst = xv;  off = u - 1048576L; }
  else if (u < 1605632L) { src = wq;  dst = bwq; off = u - 1572864L; qs = 0.18033688f; }
  else if (u < 1638400L) { src = wk;  dst = bwk; off = u - 1605632L; }
  else if (u < 1671168L) { src = wv;  dst = bwv; off = u - 1638400L; }
  else if (u < 1703936L) { src = wo;  dst = bwo; off = u - 1671168L; }
  else if (u < 1736696L) { src = wp;  dst = bwp; off = u - 1703936L; }
  else {  // zero-fill Wp pad row 4095
    long o = (u - 1736696L) * 8 + 262080L;
    uint4 z = {0u, 0u, 0u, 0u};
    *(uint4*)(bwp + o) = z;
    return;
  }
  const float4* s4 = (const float4*)(src + off * 8);
  float4 a = s4[0], b = s4[1];
  uint32_t p0 = pkbf(a.x * qs, a.y * qs);
  uint32_t p1 = pkbf(a.z * qs, a.w * qs);
  uint32_t p2 = pkbf(b.x * qs, b.y * qs);
  uint32_t p3 = pkbf(b.z * qs, b.w * qs);
  uint4 o = {p0, p1, p2, p3};
  *(uint4*)(dst + off * 8) = o;
}

// ---------------------------------------------------------------------------
// 64x64-tile GEMM core (C = A @ W^T), 4 waves, each wave one 32x32 quadrant.
// ---------------------------------------------------------------------------
__device__ __forceinline__ void gemm64_core(
    const u16* __restrict__ A, const u16* __restrict__ W, int m0, int n0,
    u16* Al, u16* Bl, int tid, f32x16& acc) {
  const int lane = tid & 63, w = tid >> 6;
  const int wi = w >> 1, wj = w & 1;
  const int l31 = lane & 31, lh = lane >> 5;
  const int r = tid >> 2, ch = tid & 3;
  const int gch = ch ^ ((r >> 1) & 3);
  for (int kb = 0; kb < 16; ++kb) {
    gl_lds16(A + (long)(m0 + r) * 512 + kb * 32 + gch * 8, (char*)Al + w * 64 * 16);
    gl_lds16(W + (long)(n0 + r) * 512 + kb * 32 + gch * 8, (char*)Bl + w * 64 * 16);
    __syncthreads();
    bf16x8 af[2], bfr[2];
#pragma unroll
    for (int ks = 0; ks < 2; ++ks) {
      int c2 = 2 * ks + lh;
      int rA = 32 * wi + l31;
      int rB = 32 * wj + l31;
      af[ks]  = *(const bf16x8*)((char*)Al + (rA * 4 + (c2 ^ ((rA >> 1) & 3))) * 16);
      bfr[ks] = *(const bf16x8*)((char*)Bl + (rB * 4 + (c2 ^ ((rB >> 1) & 3))) * 16);
    }
#pragma unroll
    for (int ks = 0; ks < 2; ++ks)
      acc = __builtin_amdgcn_mfma_f32_32x32x16_bf16(af[ks], bfr[ks], acc, 0, 0, 0);
    __syncthreads();
  }
}

// gemm_bt: final projection, fp32 out row-major. 1024 blocks.
__global__ __launch_bounds__(256, 4) void gemm_bt(
    const u16* __restrict__ A, const u16* __restrict__ W, const float* __restrict__ bias,
    float* __restrict__ ofp) {
  __shared__ u16 Al[64 * 32];
  __shared__ u16 Bl[64 * 32];
  const int tid = threadIdx.x;
  const int lane = tid & 63, w = tid >> 6;
  const int wi = w >> 1, wj = w & 1;
  const int l31 = lane & 31, lh = lane >> 5;
  const int u = (blockIdx.x & 7) * 128 + (blockIdx.x >> 3);
  const int m0 = (u >> 3) * 64, n0 = (u & 7) * 64;

  float bv = bias[n0 + 32 * wj + l31];
  f32x16 acc;
#pragma unroll
  for (int rr = 0; rr < 16; ++rr) acc[rr] = bv;

  gemm64_core(A, W, m0, n0, Al, Bl, tid, acc);

  int n = n0 + 32 * wj + l31;
#pragma unroll
  for (int rr = 0; rr < 16; ++rr) {
    int row = m0 + 32 * wi + (rr & 3) + 8 * (rr >> 2) + 4 * lh;
    ofp[(long)row * 512 + n] = acc[rr];
  }
}

// qkv_gemm: 3072 blocks (3 mats x 1024), bf16 out in (b,h,l,d).
__global__ __launch_bounds__(256, 4) void qkv_gemm(
    const u16* __restrict__ xq, const u16* __restrict__ xk, const u16* __restrict__ xv,
    const u16* __restrict__ wqp, const u16* __restrict__ wkp, const u16* __restrict__ wvp,
    const float* __restrict__ bq, const float* __restrict__ bk, const float* __restrict__ bv,
    u16* __restrict__ oq, u16* __restrict__ ok, u16* __restrict__ ov) {
  __shared__ u16 Al[64 * 32];
  __shared__ u16 Bl[64 * 32];
  const int mat = blockIdx.x >> 10;
  const int t = blockIdx.x & 1023;
  const u16* A = (mat == 0) ? xq : (mat == 1) ? xk : xv;
  const u16* W = (mat == 0) ? wqp : (mat == 1) ? wkp : wvp;
  const float* bias = (mat == 0) ? bq : (mat == 1) ? bk : bv;
  u16* obf = (mat == 0) ? oq : (mat == 1) ? ok : ov;
  const float bsc = (mat == 0) ? 0.18033688f : 1.0f;

  const int tid = threadIdx.x;
  const int lane = tid & 63, w = tid >> 6;
  const int wi = w >> 1, wj = w & 1;
  const int l31 = lane & 31, lh = lane >> 5;
  const int u = (t & 7) * 128 + (t >> 3);
  const int m0 = (u >> 3) * 64, n0 = (u & 7) * 64;

  float bvv = bias[n0 + 32 * wj + l31] * bsc;
  f32x16 acc;
#pragma unroll
  for (int rr = 0; rr < 16; ++rr) acc[rr] = bvv;

  gemm64_core(A, W, m0, n0, Al, Bl, tid, acc);

  int n = n0 + 32 * wj + l31;
  int h = n >> 6, d = n & 63;
#pragma unroll
  for (int rr = 0; rr < 16; ++rr) {
    int row = m0 + 32 * wi + (rr & 3) + 8 * (rr >> 2) + 4 * lh;
    int b = row >> 11, l = row & 2047;
    obf[(((long)(b * 8 + h)) * 2048 + l) * 64 + d] = f2bf(acc[rr]);
  }
}

// ---------------------------------------------------------------------------
// Attention v4: barrier-free main loop, spill-free register budget.
// One block per (b,h, 64-row i-tile); 4 independent waves; wave (wi,wj) owns
// rows [r0,r0+32) x cols [1024wj+32t). Per step: wave-local skew gather from
// TWO rolling P tiles (one cndmask + one ds_bpermute per reg, f32), then the
// score MFMA chain on top (P as C-init), exp2, rsum. Tile t+2 is computed
// into the buffer retired by this step's gather (2-buffer rotation, statically
// named via 2-unrolled loop -> no runtime indexing, nothing spillable).
// Live state: aq(16) + PA(16) + PB(16) + rsum(16) + kf(16) + accS(16) ~ 96+T.
// Window math: W(j,r)=2047+j-r; wb=2016+c0b-r0; idx=31+l31-lrr-4lh in [0,62];
// max Wp row touched = 4095 (zero pad row), bias clamp 4094 (never read).
// ---------------------------------------------------------------------------
#define ATTN_STEP(T, X, Y, DO_NEXT)                                              \
  do {                                                                           \
    const int t_ = (T);                                                          \
    const u16* kp_ = kb + (long)(c0b + 32 * t_ + l31) * 64 + lh * 8;             \
    bf16x8 kf0 = *(const bf16x8*)(kp_);                                          \
    bf16x8 kf1 = *(const bf16x8*)(kp_ + 16);                                     \
    bf16x8 kf2 = *(const bf16x8*)(kp_ + 32);                                     \
    bf16x8 kf3 = *(const bf16x8*)(kp_ + 48);                                     \
    f32x16 accS;                                                                 \
    _Pragma("unroll")                                                            \
    for (int r = 0; r < 16; ++r) {                                               \
      const int lrr = (r & 3) + 8 * (r >> 2);                                    \
      float M = (tsel >= 31 - lrr) ? X[r] : Y[r];                                \
      int gi = __builtin_amdgcn_ds_bpermute((((lbb - lrr) & 31) << 2) + hb,      \
                                            __float_as_int(M));                  \
      accS[r] = __int_as_float(gi);                                              \
    }                                                                            \
    if (DO_NEXT) {                                                               \
      int wr_ = wb + 32 * (t_ + 2) + l31;                                        \
      const u16* bp_ = wpw + (long)wr_ * 64 + lh * 8;                            \
      bf16x8 bw0 = *(const bf16x8*)(bp_);                                        \
      bf16x8 bw1 = *(const bf16x8*)(bp_ + 16);                                   \
      bf16x8 bw2 = *(const bf16x8*)(bp_ + 32);                                   \
      bf16x8 bw3 = *(const bf16x8*)(bp_ + 48);                                   \
      float bv_ = wpb[wr_ > 4094 ? 4094 : wr_] * 1.44269504f;                    \
      _Pragma("unroll")                                                          \
      for (int r = 0; r < 16; ++r) X[r] = bv_;                                   \
      X = __builtin_amdgcn_mfma_f32_32x32x16_bf16(aq0, bw0, X, 0, 0, 0);         \
      X = __builtin_amdgcn_mfma_f32_32x32x16_bf16(aq1, bw1, X, 0, 0, 0);         \
      X = __builtin_amdgcn_mfma_f32_32x32x16_bf16(aq2, bw2, X, 0, 0, 0);         \
      X = __builtin_amdgcn_mfma_f32_32x32x16_bf16(aq3, bw3, X, 0, 0, 0);         \
    }                                                                            \
    accS = __builtin_amdgcn_mfma_f32_32x32x16_bf16(aq0, kf0, accS, 0, 0, 0);     \
    accS = __builtin_amdgcn_mfma_f32_32x32x16_bf16(aq1, kf1, accS, 0, 0, 0);     \
    accS = __builtin_amdgcn_mfma_f32_32x32x16_bf16(aq2, kf2, accS, 0, 0, 0);     \
    accS = __builtin_amdgcn_mfma_f32_32x32x16_bf16(aq3, kf3, accS, 0, 0, 0);     \
    _Pragma("unroll")                                                            \
    for (int r = 0; r < 16; ++r) rsum[r] += exp2v(accS[r]);                      \
    if (t_ == td) {                                                              \
      _Pragma("unroll")                                                          \
      for (int r = 0; r < 16; ++r) {                                             \
        const int lrr = (r & 3) + 8 * (r >> 2);                                  \
        if (l31 == lrr + 4 * lh) sdiag[32 * wi + l31] = accS[r];                 \
      }                                                                          \
    }                                                                            \
  } while (0)

__global__ __launch_bounds__(256, 3) void attn_kernel(
    const u16* __restrict__ qw, const u16* __restrict__ kw, const u16* __restrict__ vw,
    const u16* __restrict__ wpw, const float* __restrict__ wpb, u16* __restrict__ outp) {
  __shared__ float sdiag[64];
  __shared__ float rssum[128];
  __shared__ float attw[64];

  const int tid = threadIdx.x, lane = tid & 63, w = tid >> 6;
  const int wi = w >> 1, wj = w & 1;
  const int sbi = blockIdx.x;
  const int kk_ = sbi >> 3;
  const int bh = (sbi & 7) + 8 * (kk_ >> 5);   // XCD swizzle: 32 i-tiles/bh per XCD
  const int it = kk_ & 31;
  const int i0 = it * 64;
  const u16* qb = qw + (long)bh * 2048 * 64;
  const u16* kb = kw + (long)bh * 2048 * 64;
  const u16* vb = vw + (long)bh * 2048 * 64;

  const int l31 = lane & 31, lh = lane >> 5;
  const int r0 = i0 + 32 * wi;
  const int c0b = 1024 * wj;
  const int wb = 2016 + c0b - r0;              // window base at t=0
  const int tsel = l31 + 4 * lh;               // A/B select key
  const int lbb = l31 + 31 - 4 * lh;           // bpermute index base
  const int hb = 128 * lh;                     // byte base of this 32-half

  // A-fragments: Q rows r0 + l31, full K=64 (log2e/8 pre-scaled)
  bf16x8 aq0, aq1, aq2, aq3;
  {
    const u16* p = qb + (long)(r0 + l31) * 64 + lh * 8;
    aq0 = *(const bf16x8*)(p);
    aq1 = *(const bf16x8*)(p + 16);
    aq2 = *(const bf16x8*)(p + 32);
    aq3 = *(const bf16x8*)(p + 48);
  }

  float rsum[16];
#pragma unroll
  for (int r = 0; r < 16; ++r) rsum[r] = 0.f;

  int td = -1;  // iteration holding this wave's diagonal (if any)
  {
    int tdn = r0 - c0b;
    if (tdn >= 0 && tdn < 1024) td = tdn >> 5;
  }

  // prologue: window tiles 0 and 1
  f32x16 PA, PB;
  {
    int wr = wb + l31;
    const u16* bp = wpw + (long)wr * 64 + lh * 8;
    bf16x8 b0 = *(const bf16x8*)(bp), b1 = *(const bf16x8*)(bp + 16);
    bf16x8 b2 = *(const bf16x8*)(bp + 32), b3 = *(const bf16x8*)(bp + 48);
    float bv = wpb[wr > 4094 ? 4094 : wr] * 1.44269504f;
#pragma unroll
    for (int r = 0; r < 16; ++r) PA[r] = bv;
    PA = __builtin_amdgcn_mfma_f32_32x32x16_bf16(aq0, b0, PA, 0, 0, 0);
    PA = __builtin_amdgcn_mfma_f32_32x32x16_bf16(aq1, b1, PA, 0, 0, 0);
    PA = __builtin_amdgcn_mfma_f32_32x32x16_bf16(aq2, b2, PA, 0, 0, 0);
    PA = __builtin_amdgcn_mfma_f32_32x32x16_bf16(aq3, b3, PA, 0, 0, 0);
  }
  {
    int wr = wb + 32 + l31;
    const u16* bp = wpw + (long)wr * 64 + lh * 8;
    bf16x8 b0 = *(const bf16x8*)(bp), b1 = *(const bf16x8*)(bp + 16);
    bf16x8 b2 = *(const bf16x8*)(bp + 32), b3 = *(const bf16x8*)(bp + 48);
    float bv = wpb[wr > 4094 ? 4094 : wr] * 1.44269504f;
#pragma unroll
    for (int r = 0; r < 16; ++r) PB[r] = bv;
    PB = __builtin_amdgcn_mfma_f32_32x32x16_bf16(aq0, b0, PB, 0, 0, 0);
    PB = __builtin_amdgcn_mfma_f32_32x32x16_bf16(aq1, b1, PB, 0, 0, 0);
    PB = __builtin_amdgcn_mfma_f32_32x32x16_bf16(aq2, b2, PB, 0, 0, 0);
    PB = __builtin_amdgcn_mfma_f32_32x32x16_bf16(aq3, b3, PB, 0, 0, 0);
  }

  // main loop: 2-unrolled so the 2-buffer rotation is statically named.
  // step t: gather from (tile t, tile t+1), then tile t+2 overwrites slot of t.
  for (int tt = 0; tt < 30; tt += 2) {
    ATTN_STEP(tt,     PA, PB, true);   // PA <- tile tt+2
    ATTN_STEP(tt + 1, PB, PA, true);   // PB <- tile tt+3
  }
  ATTN_STEP(30, PA, PB, true);         // PA <- tile 32
  ATTN_STEP(31, PB, PA, false);

  // reduce row partials across the 32 lanes sharing each row
#pragma unroll
  for (int r = 0; r < 16; ++r) {
    float v = rsum[r];
    v += __shfl_xor(v, 1);
    v += __shfl_xor(v, 2);
    v += __shfl_xor(v, 4);
    v += __shfl_xor(v, 8);
    v += __shfl_xor(v, 16);
    rsum[r] = v;
  }
  if (l31 == 0) {
#pragma unroll
    for (int r = 0; r < 16; ++r) {
      int lr = (r & 3) + 8 * (r >> 2) + 4 * lh;
      rssum[(32 * wi + lr) * 2 + wj] = rsum[r];
    }
  }
  __syncthreads();
  if (tid < 64) {
    float S = rssum[2 * tid] + rssum[2 * tid + 1];
    attw[tid] = exp2v(sdiag[tid]) / S;
  }
  __syncthreads();
  // out_pre[b*2048 + i][h*64 + d] = diag * v   (bf16)
  {
    int r = tid >> 2, dd = (tid & 3) * 16;
    float a = attw[r];
    int b = bh >> 3, h = bh & 7;
    const u16* vp = vb + (long)(i0 + r) * 64 + dd;
    u16* op = outp + ((long)(b * 2048 + i0 + r)) * 512 + h * 64 + dd;
    uint4 v0 = *(const uint4*)vp;
    uint4 v1 = *(const uint4*)(vp + 8);
    uint32_t vin[8] = {v0.x, v0.y, v0.z, v0.w, v1.x, v1.y, v1.z, v1.w};
    uint32_t vout[8];
#pragma unroll
    for (int e = 0; e < 8; ++e) {
      float lo = bf2f((u16)(vin[e] & 0xffffu)) * a;
      float hi = bf2f((u16)(vin[e] >> 16)) * a;
      vout[e] = pkbf(lo, hi);
    }
    uint4 o0 = {vout[0], vout[1], vout[2], vout[3]};
    uint4 o1 = {vout[4], vout[5], vout[6], vout[7]};
    *(uint4*)op = o0;
    *(uint4*)(op + 8) = o1;
  }
}

// ---------------------------------------------------------------------------
extern "C" void kernel_launch(void* const* d_in, const int* in_sizes, int n_in,
                              void* d_out, int out_size, void* d_ws, size_t ws_size,
                              hipStream_t stream) {
  (void)in_sizes; (void)n_in; (void)out_size; (void)ws_size;
  const float* q_in = (const float*)d_in[0];
  const float* k_in = (const float*)d_in[1];
  const float* v_in = (const float*)d_in[2];
  const float* Wq_w = (const float*)d_in[3];
  const float* Wq_b = (const float*)d_in[4];
  const float* Wk_w = (const float*)d_in[5];
  const float* Wk_b = (const float*)d_in[6];
  const float* Wv_w = (const float*)d_in[7];
  const float* Wv_b = (const float*)d_in[8];
  const float* Wo_w = (const float*)d_in[9];
  const float* Wo_b = (const float*)d_in[10];
  const float* Wp_w = (const float*)d_in[11];
  const float* Wp_b = (const float*)d_in[12];

  char* ws = (char*)d_ws;
  u16* xq   = (u16*)(ws + 0);         // 8 MB  bf16 q_in
  u16* xk   = (u16*)(ws + 8388608);   // 8 MB
  u16* xv   = (u16*)(ws + 16777216);  // 8 MB
  u16* wq   = (u16*)(ws + 25165824);  // 512 KB each
  u16* wk   = (u16*)(ws + 25690112);
  u16* wv   = (u16*)(ws + 26214400);
  u16* wo   = (u16*)(ws + 26738688);
  u16* wp   = (u16*)(ws + 27262976);  // 4096x64 bf16 (row 4095 zero)
  u16* q_ws = (u16*)(ws + 27787264);  // (b,h,l,d) bf16, pre-scaled log2e/8
  u16* k_ws = (u16*)(ws + 36175872);
  u16* v_ws = (u16*)(ws + 44564480);
  u16* opre = (u16*)(ws + 52953088);  // (b*l, h*d) bf16 diag-scaled v

  prep_kernel<<<6784, 256, 0, stream>>>(q_in, k_in, v_in, Wq_w, Wk_w, Wv_w, Wo_w, Wp_w,
                                        xq, xk, xv, wq, wk, wv, wo, wp);
  qkv_gemm<<<3072, 256, 0, stream>>>(xq, xk, xv, wq, wk, wv, Wq_b, Wk_b, Wv_b,
                                     q_ws, k_ws, v_ws);
  attn_kernel<<<1024, 256, 0, stream>>>(q_ws, k_ws, v_ws, wp, Wp_b, opre);
  gemm_bt<<<1024, 256, 0, stream>>>(opre, wo, Wo_b, (float*)d_out);
}

// Round 5
// 279.976 us; speedup vs baseline: 1.0807x; 1.0154x over previous
//
#include <hip/hip_runtime.h>
#include <cstdint>

// B=4, L=2048, H=512, HEADS=8, D=64.
// Only the DIAGONAL of softmax(scores) is consumed:
//   diag_i = exp(s_ii) / sum_j exp(s_ij),
//   s_ij = q_i.k_j + q_i.Wp[2047+j-i (padded)] + Wp_b[2047+j-i]
// Logits in log2 units (q pre-scaled by log2e/8 via prep-scaled Wq, bias by log2e).

typedef unsigned short u16;
typedef __bf16 bf16x8 __attribute__((ext_vector_type(8)));
typedef __bf16 bf16x2 __attribute__((ext_vector_type(2)));
typedef float  f32x16 __attribute__((ext_vector_type(16)));
typedef uint32_t __attribute__((address_space(1))) as1_u32;
typedef uint32_t __attribute__((address_space(3))) as3_u32;

__device__ __forceinline__ u16 f2bf(float f) {
  __bf16 h = (__bf16)f;
  return __builtin_bit_cast(u16, h);
}
__device__ __forceinline__ uint32_t pkbf(float a, float b) {
  bf16x2 v; v[0] = (__bf16)a; v[1] = (__bf16)b;
  return __builtin_bit_cast(uint32_t, v);
}
__device__ __forceinline__ float bf2f(u16 u) {
  return __uint_as_float(((uint32_t)u) << 16);
}
__device__ __forceinline__ float exp2v(float x) {
  float r;
  asm("v_exp_f32 %0, %1" : "=v"(r) : "v"(x));
  return r;
}
__device__ __forceinline__ void gl_lds16(const void* g, void* l) {
  __builtin_amdgcn_global_load_lds((const as1_u32*)g, (as3_u32*)l, 16, 0, 0);
}

// ---------------------------------------------------------------------------
// Prep: fp32 -> bf16 for q_in/k_in/v_in, Wq/Wk/Wv/Wo, Wp (padded to 4096 rows)
// Wq is pre-scaled by log2e/8 so the QKV epilogue needs no multiply.
// ---------------------------------------------------------------------------
__global__ __launch_bounds__(256) void prep_kernel(
    const float* __restrict__ qin, const float* __restrict__ kin, const float* __restrict__ vin,
    const float* __restrict__ wq,  const float* __restrict__ wk,  const float* __restrict__ wv,
    const float* __restrict__ wo,  const float* __restrict__ wp,
    u16* __restrict__ xq, u16* __restrict__ xk, u16* __restrict__ xv,
    u16* __restrict__ bwq, u16* __restrict__ bwk, u16* __restrict__ bwv,
    u16* __restrict__ bwo, u16* __restrict__ bwp) {
  long u = (long)blockIdx.x * 256 + threadIdx.x;
  const float* src; u16* dst; long off; float qs = 1.0f;
  if      (u < 524288L)  { src = qin; dst = xq;  off = u; }
  else if (u < 1048576L) { src = kin; dst = xk;  off = u - 524288L; }
  else if (u < 1572864L) { src = vin; dst = xv;  off = u - 1048576L; }
  else if (u < 1605632L) { src = wq;  dst = bwq; off = u - 1572864L; qs = 0.18033688f; }
  else if (u < 1638400L) { src = wk;  dst = bwk; off = u - 1605632L; }
  else if (u < 1671168L) { src = wv;  dst = bwv; off = u - 1638400L; }
  else if (u < 1703936L) { src = wo;  dst = bwo; off = u - 1671168L; }
  else if (u < 1736696L) { src = wp;  dst = bwp; off = u - 1703936L; }
  else {  // zero-fill Wp pad row 4095
    long o = (u - 1736696L) * 8 + 262080L;
    uint4 z = {0u, 0u, 0u, 0u};
    *(uint4*)(bwp + o) = z;
    return;
  }
  const float4* s4 = (const float4*)(src + off * 8);
  float4 a = s4[0], b = s4[1];
  uint32_t p0 = pkbf(a.x * qs, a.y * qs);
  uint32_t p1 = pkbf(a.z * qs, a.w * qs);
  uint32_t p2 = pkbf(b.x * qs, b.y * qs);
  uint32_t p3 = pkbf(b.z * qs, b.w * qs);
  uint4 o = {p0, p1, p2, p3};
  *(uint4*)(dst + off * 8) = o;
}

// ---------------------------------------------------------------------------
// 64x64-tile GEMM core (C = A @ W^T), 4 waves, each wave one 32x32 quadrant.
// ---------------------------------------------------------------------------
__device__ __forceinline__ void gemm64_core(
    const u16* __restrict__ A, const u16* __restrict__ W, int m0, int n0,
    u16* Al, u16* Bl, int tid, f32x16& acc) {
  const int lane = tid & 63, w = tid >> 6;
  const int wi = w >> 1, wj = w & 1;
  const int l31 = lane & 31, lh = lane >> 5;
  const int r = tid >> 2, ch = tid & 3;
  const int gch = ch ^ ((r >> 1) & 3);
  for (int kb = 0; kb < 16; ++kb) {
    gl_lds16(A + (long)(m0 + r) * 512 + kb * 32 + gch * 8, (char*)Al + w * 64 * 16);
    gl_lds16(W + (long)(n0 + r) * 512 + kb * 32 + gch * 8, (char*)Bl + w * 64 * 16);
    __syncthreads();
    bf16x8 af[2], bfr[2];
#pragma unroll
    for (int ks = 0; ks < 2; ++ks) {
      int c2 = 2 * ks + lh;
      int rA = 32 * wi + l31;
      int rB = 32 * wj + l31;
      af[ks]  = *(const bf16x8*)((char*)Al + (rA * 4 + (c2 ^ ((rA >> 1) & 3))) * 16);
      bfr[ks] = *(const bf16x8*)((char*)Bl + (rB * 4 + (c2 ^ ((rB >> 1) & 3))) * 16);
    }
#pragma unroll
    for (int ks = 0; ks < 2; ++ks)
      acc = __builtin_amdgcn_mfma_f32_32x32x16_bf16(af[ks], bfr[ks], acc, 0, 0, 0);
    __syncthreads();
  }
}

// gemm_bt: final projection, fp32 out row-major. 1024 blocks.
__global__ __launch_bounds__(256, 4) void gemm_bt(
    const u16* __restrict__ A, const u16* __restrict__ W, const float* __restrict__ bias,
    float* __restrict__ ofp) {
  __shared__ u16 Al[64 * 32];
  __shared__ u16 Bl[64 * 32];
  const int tid = threadIdx.x;
  const int lane = tid & 63, w = tid >> 6;
  const int wi = w >> 1, wj = w & 1;
  const int l31 = lane & 31, lh = lane >> 5;
  const int u = (blockIdx.x & 7) * 128 + (blockIdx.x >> 3);
  const int m0 = (u >> 3) * 64, n0 = (u & 7) * 64;

  float bv = bias[n0 + 32 * wj + l31];
  f32x16 acc;
#pragma unroll
  for (int rr = 0; rr < 16; ++rr) acc[rr] = bv;

  gemm64_core(A, W, m0, n0, Al, Bl, tid, acc);

  int n = n0 + 32 * wj + l31;
#pragma unroll
  for (int rr = 0; rr < 16; ++rr) {
    int row = m0 + 32 * wi + (rr & 3) + 8 * (rr >> 2) + 4 * lh;
    ofp[(long)row * 512 + n] = acc[rr];
  }
}

// qkv_gemm: 3072 blocks (3 mats x 1024), bf16 out in (b,h,l,d).
__global__ __launch_bounds__(256, 4) void qkv_gemm(
    const u16* __restrict__ xq, const u16* __restrict__ xk, const u16* __restrict__ xv,
    const u16* __restrict__ wqp, const u16* __restrict__ wkp, const u16* __restrict__ wvp,
    const float* __restrict__ bq, const float* __restrict__ bk, const float* __restrict__ bv,
    u16* __restrict__ oq, u16* __restrict__ ok, u16* __restrict__ ov) {
  __shared__ u16 Al[64 * 32];
  __shared__ u16 Bl[64 * 32];
  const int mat = blockIdx.x >> 10;
  const int t = blockIdx.x & 1023;
  const u16* A = (mat == 0) ? xq : (mat == 1) ? xk : xv;
  const u16* W = (mat == 0) ? wqp : (mat == 1) ? wkp : wvp;
  const float* bias = (mat == 0) ? bq : (mat == 1) ? bk : bv;
  u16* obf = (mat == 0) ? oq : (mat == 1) ? ok : ov;
  const float bsc = (mat == 0) ? 0.18033688f : 1.0f;

  const int tid = threadIdx.x;
  const int lane = tid & 63, w = tid >> 6;
  const int wi = w >> 1, wj = w & 1;
  const int l31 = lane & 31, lh = lane >> 5;
  const int u = (t & 7) * 128 + (t >> 3);
  const int m0 = (u >> 3) * 64, n0 = (u & 7) * 64;

  float bvv = bias[n0 + 32 * wj + l31] * bsc;
  f32x16 acc;
#pragma unroll
  for (int rr = 0; rr < 16; ++rr) acc[rr] = bvv;

  gemm64_core(A, W, m0, n0, Al, Bl, tid, acc);

  int n = n0 + 32 * wj + l31;
  int h = n >> 6, d = n & 63;
#pragma unroll
  for (int rr = 0; rr < 16; ++rr) {
    int row = m0 + 32 * wi + (rr & 3) + 8 * (rr >> 2) + 4 * lh;
    int b = row >> 11, l = row & 2047;
    obf[(((long)(b * 8 + h)) * 2048 + l) * 64 + d] = f2bf(acc[rr]);
  }
}

// ---------------------------------------------------------------------------
// Attention v5: barrier-free + DOUBLED block parallelism + K prefetch.
// 2048 blocks: (b,h, 64-row i-tile, column HALF). Wave (wi,wj) owns rows
// [r0,r0+32) x cols c0 = 1024*half + 512*wj + 32t, t=0..15 (16 steps).
// Per step: wave-local skew gather from two rolling P tiles (cndmask +
// ds_bpermute per reg, f32), score MFMA chain with K fragments PRELOADED
// LAST STEP (kfa/kfb parity double-buffer -> K L2 latency off the critical
// path), exp2, rsum. P tile t+2 overwrites the buffer retired by the gather.
// Partial row-sums -> psum global (no atomics: one block per (tile,half));
// diagonal -> pdiag global (exactly one half-block holds it).
// Window math: W(j,r)=2047+j-r; wb=2016+c0-r0; idx=31+l31-lrr-4lh in [0,62];
// max Wp row touched = 4095 (zero pad row), bias clamp 4094 (never read).
// ---------------------------------------------------------------------------
#define ATTN_STEP(T, X, Y, KC, KN, DO_NEXT, DO_KF)                               \
  do {                                                                           \
    const int t_ = (T);                                                          \
    f32x16 accS;                                                                 \
    _Pragma("unroll")                                                            \
    for (int r = 0; r < 16; ++r) {                                               \
      const int lrr = (r & 3) + 8 * (r >> 2);                                    \
      float M = (tsel >= 31 - lrr) ? X[r] : Y[r];                                \
      int gi = __builtin_amdgcn_ds_bpermute((((lbb - lrr) & 31) << 2) + hb,      \
                                            __float_as_int(M));                  \
      accS[r] = __int_as_float(gi);                                              \
    }                                                                            \
    if (DO_KF) {                                                                 \
      const u16* kp_ = kb + (long)(c0 + 32 * (t_ + 1) + l31) * 64 + lh * 8;      \
      KN##0 = *(const bf16x8*)(kp_);                                             \
      KN##1 = *(const bf16x8*)(kp_ + 16);                                        \
      KN##2 = *(const bf16x8*)(kp_ + 32);                                        \
      KN##3 = *(const bf16x8*)(kp_ + 48);                                        \
    }                                                                            \
    if (DO_NEXT) {                                                               \
      int wr_ = wb + 32 * (t_ + 2) + l31;                                        \
      const u16* bp_ = wpw + (long)wr_ * 64 + lh * 8;                            \
      bf16x8 bw0 = *(const bf16x8*)(bp_);                                        \
      bf16x8 bw1 = *(const bf16x8*)(bp_ + 16);                                   \
      bf16x8 bw2 = *(const bf16x8*)(bp_ + 32);                                   \
      bf16x8 bw3 = *(const bf16x8*)(bp_ + 48);                                   \
      float bv_ = wpb[wr_ > 4094 ? 4094 : wr_] * 1.44269504f;                    \
      _Pragma("unroll")                                                          \
      for (int r = 0; r < 16; ++r) X[r] = bv_;                                   \
      X = __builtin_amdgcn_mfma_f32_32x32x16_bf16(aq0, bw0, X, 0, 0, 0);         \
      X = __builtin_amdgcn_mfma_f32_32x32x16_bf16(aq1, bw1, X, 0, 0, 0);         \
      X = __builtin_amdgcn_mfma_f32_32x32x16_bf16(aq2, bw2, X, 0, 0, 0);         \
      X = __builtin_amdgcn_mfma_f32_32x32x16_bf16(aq3, bw3, X, 0, 0, 0);         \
    }                                                                            \
    accS = __builtin_amdgcn_mfma_f32_32x32x16_bf16(aq0, KC##0, accS, 0, 0, 0);   \
    accS = __builtin_amdgcn_mfma_f32_32x32x16_bf16(aq1, KC##1, accS, 0, 0, 0);   \
    accS = __builtin_amdgcn_mfma_f32_32x32x16_bf16(aq2, KC##2, accS, 0, 0, 0);   \
    accS = __builtin_amdgcn_mfma_f32_32x32x16_bf16(aq3, KC##3, accS, 0, 0, 0);   \
    _Pragma("unroll")                                                            \
    for (int r = 0; r < 16; ++r) rsum[r] += exp2v(accS[r]);                      \
    if (t_ == td) {                                                              \
      _Pragma("unroll")                                                          \
      for (int r = 0; r < 16; ++r) {                                             \
        const int lrr = (r & 3) + 8 * (r >> 2);                                  \
        if (l31 == lrr + 4 * lh) pdiag[tb64 + 32 * wi + l31] = accS[r];          \
      }                                                                          \
    }                                                                            \
  } while (0)

__global__ __launch_bounds__(256, 3) void attn_kernel(
    const u16* __restrict__ qw, const u16* __restrict__ kw,
    const u16* __restrict__ wpw, const float* __restrict__ wpb,
    float* __restrict__ psum, float* __restrict__ pdiag) {
  __shared__ float rssum[128];

  const int tid = threadIdx.x, lane = tid & 63, w = tid >> 6;
  const int wi = w >> 1, wj = w & 1;
  // XCD swizzle: 2048 blocks; XCD x gets bh in {x, x+8, x+16, x+24}.
  const int sbi = blockIdx.x;
  const int x = sbi & 7, g = sbi >> 3;          // g in 0..255
  const int bh = x + 8 * (g >> 6);
  const int rem = g & 63;
  const int it = rem >> 1, half = rem & 1;
  const int i0 = it * 64;
  const u16* qb = qw + (long)bh * 2048 * 64;
  const u16* kb = kw + (long)bh * 2048 * 64;

  const int l31 = lane & 31, lh = lane >> 5;
  const int r0 = i0 + 32 * wi;
  const int c0 = 1024 * half + 512 * wj;
  const int wb = 2016 + c0 - r0;               // window base at t=0
  const int tsel = l31 + 4 * lh;               // A/B select key
  const int lbb = l31 + 31 - 4 * lh;           // bpermute index base
  const int hb = 128 * lh;                     // byte base of this 32-half
  const long tb64 = (long)(bh * 32 + it) * 64;

  // A-fragments: Q rows r0 + l31, full K=64 (log2e/8 pre-scaled)
  bf16x8 aq0, aq1, aq2, aq3;
  {
    const u16* p = qb + (long)(r0 + l31) * 64 + lh * 8;
    aq0 = *(const bf16x8*)(p);
    aq1 = *(const bf16x8*)(p + 16);
    aq2 = *(const bf16x8*)(p + 32);
    aq3 = *(const bf16x8*)(p + 48);
  }

  float rsum[16];
#pragma unroll
  for (int r = 0; r < 16; ++r) rsum[r] = 0.f;

  int td = -1;  // step holding this wave's diagonal (if any)
  {
    int tdn = r0 - c0;
    if (tdn >= 0 && tdn < 512) td = tdn >> 5;
  }

  // K prefetch for step 0
  bf16x8 kfa0, kfa1, kfa2, kfa3, kfb0, kfb1, kfb2, kfb3;
  {
    const u16* kp = kb + (long)(c0 + l31) * 64 + lh * 8;
    kfa0 = *(const bf16x8*)(kp);
    kfa1 = *(const bf16x8*)(kp + 16);
    kfa2 = *(const bf16x8*)(kp + 32);
    kfa3 = *(const bf16x8*)(kp + 48);
  }

  // prologue: window tiles 0 and 1
  f32x16 PA, PB;
  {
    int wr = wb + l31;
    const u16* bp = wpw + (long)wr * 64 + lh * 8;
    bf16x8 b0 = *(const bf16x8*)(bp), b1 = *(const bf16x8*)(bp + 16);
    bf16x8 b2 = *(const bf16x8*)(bp + 32), b3 = *(const bf16x8*)(bp + 48);
    float bv = wpb[wr > 4094 ? 4094 : wr] * 1.44269504f;
#pragma unroll
    for (int r = 0; r < 16; ++r) PA[r] = bv;
    PA = __builtin_amdgcn_mfma_f32_32x32x16_bf16(aq0, b0, PA, 0, 0, 0);
    PA = __builtin_amdgcn_mfma_f32_32x32x16_bf16(aq1, b1, PA, 0, 0, 0);
    PA = __builtin_amdgcn_mfma_f32_32x32x16_bf16(aq2, b2, PA, 0, 0, 0);
    PA = __builtin_amdgcn_mfma_f32_32x32x16_bf16(aq3, b3, PA, 0, 0, 0);
  }
  {
    int wr = wb + 32 + l31;
    const u16* bp = wpw + (long)wr * 64 + lh * 8;
    bf16x8 b0 = *(const bf16x8*)(bp), b1 = *(const bf16x8*)(bp + 16);
    bf16x8 b2 = *(const bf16x8*)(bp + 32), b3 = *(const bf16x8*)(bp + 48);
    float bv = wpb[wr > 4094 ? 4094 : wr] * 1.44269504f;
#pragma unroll
    for (int r = 0; r < 16; ++r) PB[r] = bv;
    PB = __builtin_amdgcn_mfma_f32_32x32x16_bf16(aq0, b0, PB, 0, 0, 0);
    PB = __builtin_amdgcn_mfma_f32_32x32x16_bf16(aq1, b1, PB, 0, 0, 0);
    PB = __builtin_amdgcn_mfma_f32_32x32x16_bf16(aq2, b2, PB, 0, 0, 0);
    PB = __builtin_amdgcn_mfma_f32_32x32x16_bf16(aq3, b3, PB, 0, 0, 0);
  }

  // main loop: 16 steps; 2-unrolled for static buffer/prefetch parity.
  // step t: gather from (tile t, tile t+1); tile t+2 overwrites slot of t;
  // K for step t+1 loads into the retired kf buffer.
  for (int tt = 0; tt < 14; tt += 2) {
    ATTN_STEP(tt,     PA, PB, kfa, kfb, true, true);   // PA <- tile tt+2
    ATTN_STEP(tt + 1, PB, PA, kfb, kfa, true, true);   // PB <- tile tt+3
  }
  ATTN_STEP(14, PA, PB, kfa, kfb, true,  true);        // PA <- tile 16
  ATTN_STEP(15, PB, PA, kfb, kfa, false, false);

  // reduce row partials across the 32 lanes sharing each row
#pragma unroll
  for (int r = 0; r < 16; ++r) {
    float v = rsum[r];
    v += __shfl_xor(v, 1);
    v += __shfl_xor(v, 2);
    v += __shfl_xor(v, 4);
    v += __shfl_xor(v, 8);
    v += __shfl_xor(v, 16);
    rsum[r] = v;
  }
  if (l31 == 0) {
#pragma unroll
    for (int r = 0; r < 16; ++r) {
      int lr = (r & 3) + 8 * (r >> 2) + 4 * lh;
      rssum[(32 * wi + lr) * 2 + wj] = rsum[r];
    }
  }
  __syncthreads();
  if (tid < 64) {
    float S = rssum[2 * tid] + rssum[2 * tid + 1];
    psum[(tb64 * 2) + half * 64 + tid] = S;   // ((bh*32+it)*2 + half)*64 + row
  }
}

// ---------------------------------------------------------------------------
// Combine: attw = exp2(diag) / (psum_half0 + psum_half1); out_pre = attw * v.
// 1024 blocks x 256 threads; each block one (bh, 64-row i-tile).
// ---------------------------------------------------------------------------
__global__ __launch_bounds__(256) void combine_kernel(
    const u16* __restrict__ vw, const float* __restrict__ psum,
    const float* __restrict__ pdiag, u16* __restrict__ outp) {
  const int u = blockIdx.x;            // bh*32 + it
  const int bh = u >> 5, it = u & 31, i0 = it * 64;
  const int tid = threadIdx.x;
  const int r = tid >> 2, dd = (tid & 3) * 16;
  float S = psum[u * 128 + r] + psum[u * 128 + 64 + r];
  float a = exp2v(pdiag[u * 64 + r]) / S;
  const int b = bh >> 3, h = bh & 7;
  const u16* vp = vw + (long)bh * 2048 * 64 + (long)(i0 + r) * 64 + dd;
  u16* op = outp + ((long)(b * 2048 + i0 + r)) * 512 + h * 64 + dd;
  uint4 v0 = *(const uint4*)vp;
  uint4 v1 = *(const uint4*)(vp + 8);
  uint32_t vin[8] = {v0.x, v0.y, v0.z, v0.w, v1.x, v1.y, v1.z, v1.w};
  uint32_t vout[8];
#pragma unroll
  for (int e = 0; e < 8; ++e) {
    float lo = bf2f((u16)(vin[e] & 0xffffu)) * a;
    float hi = bf2f((u16)(vin[e] >> 16)) * a;
    vout[e] = pkbf(lo, hi);
  }
  uint4 o0 = {vout[0], vout[1], vout[2], vout[3]};
  uint4 o1 = {vout[4], vout[5], vout[6], vout[7]};
  *(uint4*)op = o0;
  *(uint4*)(op + 8) = o1;
}

// ---------------------------------------------------------------------------
extern "C" void kernel_launch(void* const* d_in, const int* in_sizes, int n_in,
                              void* d_out, int out_size, void* d_ws, size_t ws_size,
                              hipStream_t stream) {
  (void)in_sizes; (void)n_in; (void)out_size; (void)ws_size;
  const float* q_in = (const float*)d_in[0];
  const float* k_in = (const float*)d_in[1];
  const float* v_in = (const float*)d_in[2];
  const float* Wq_w = (const float*)d_in[3];
  const float* Wq_b = (const float*)d_in[4];
  const float* Wk_w = (const float*)d_in[5];
  const float* Wk_b = (const float*)d_in[6];
  const float* Wv_w = (const float*)d_in[7];
  const float* Wv_b = (const float*)d_in[8];
  const float* Wo_w = (const float*)d_in[9];
  const float* Wo_b = (const float*)d_in[10];
  const float* Wp_w = (const float*)d_in[11];
  const float* Wp_b = (const float*)d_in[12];

  char* ws = (char*)d_ws;
  u16* xq    = (u16*)(ws + 0);         // 8 MB  bf16 q_in
  u16* xk    = (u16*)(ws + 8388608);   // 8 MB
  u16* xv    = (u16*)(ws + 16777216);  // 8 MB
  u16* wq    = (u16*)(ws + 25165824);  // 512 KB each
  u16* wk    = (u16*)(ws + 25690112);
  u16* wv    = (u16*)(ws + 26214400);
  u16* wo    = (u16*)(ws + 26738688);
  u16* wp    = (u16*)(ws + 27262976);  // 4096x64 bf16 (row 4095 zero)
  u16* q_ws  = (u16*)(ws + 27787264);  // (b,h,l,d) bf16, pre-scaled log2e/8
  u16* k_ws  = (u16*)(ws + 36175872);
  u16* v_ws  = (u16*)(ws + 44564480);
  u16* opre  = (u16*)(ws + 52953088);  // (b*l, h*d) bf16 diag-scaled v
  float* psum  = (float*)(ws + 61341696);  // 1024 x 2 x 64 f32 partial sums
  float* pdiag = (float*)(ws + 61865984);  // 1024 x 64 f32 diagonal logits

  prep_kernel<<<6784, 256, 0, stream>>>(q_in, k_in, v_in, Wq_w, Wk_w, Wv_w, Wo_w, Wp_w,
                                        xq, xk, xv, wq, wk, wv, wo, wp);
  qkv_gemm<<<3072, 256, 0, stream>>>(xq, xk, xv, wq, wk, wv, Wq_b, Wk_b, Wv_b,
                                     q_ws, k_ws, v_ws);
  attn_kernel<<<2048, 256, 0, stream>>>(q_ws, k_ws, wp, Wp_b, psum, pdiag);
  combine_kernel<<<1024, 256, 0, stream>>>(v_ws, psum, pdiag, opre);
  gemm_bt<<<1024, 256, 0, stream>>>(opre, wo, Wo_b, (float*)d_out);
}